// Round 15
// baseline (168.510 us; speedup 1.0000x reference)
//
#include <hip/hip_runtime.h>
#include <hip/hip_bf16.h>

typedef __hip_bfloat16 bf16;
typedef __attribute__((ext_vector_type(8))) short short8;
typedef __attribute__((ext_vector_type(4))) float f32x4;
typedef __attribute__((ext_vector_type(16))) float f32x16;

#define BB 4
#define CC 64
#define NN 4096           // 64*64
#define MH 512
#define MW 512
#define LS 72             // LDS row stride in bf16 elements
#define NPARTS 4          // k-split factor in k_att1 (r15: 16->4, amortize prologue)
#define NDEN 4            // den partial slices

// ---- workspace layout (BYTE offsets; ws is 256 MiB) ----
#define WB_Y1T  ((size_t)0)         // 4 MB scratch: y1t (bf16 conv1 raw)
#define WB_VIS  ((size_t)4259840)   // f32[4*4096] visatt (final, scatter)
#define WB_QIX  ((size_t)4325376)   // int[4*4096]
#define WB_KIX  ((size_t)4390912)   // int[4*4096]
#define WB_MFL  ((size_t)4456448)   // uchar[4*4096]
#define WB_CNT  ((size_t)4472832)   // int nq[4]; int nk[4]; uint vmaxbits
#define WB_WT1  ((size_t)4476992)   // bf16[9*64*64] wT1
#define WB_WT2  ((size_t)4550720)   // bf16[9*64*64] wT2
#define WB_WFB  ((size_t)4624448)   // bf16 w1b[8192]; w2b[4096]; wfb[8192]
#define WB_KC   ((size_t)5242880)   // bf16[4*4096*64] compacted normalized K rows (2 MiB)
#define WB_XT   ((size_t)8388608)   // bf16[4*4096*64] xt (pixel-major x)
#define WB_KXT  ((size_t)10485760)  // bf16[4*4096*64] kxt (conv2 RAW output)
#define WB_VT   ((size_t)12582912)  // bf16[4][64][4096] TRANSPOSED compacted V (2 MiB)
#define WB_QC   ((size_t)14680064)  // bf16[4*4096*64] compacted normalized Q rows (2 MiB)
#define WB_E    ((size_t)16777216)  // bf16 E cache: per-batch stride 32 MiB (128 MiB)
#define EB_ELEM ((size_t)16777216)  // E elements per batch (32 MiB / 2B)
#define WB_AFCP ((size_t)150994944) // bf16[4][4096][4][64] afc partials, q-major (8 MiB)
#define WB_DENP ((size_t)218103808) // f32[4][4096][4] den partials, q-major (256 KB)
#define WB_VISP ((size_t)220200960) // f32[8][4][4096] vis partials (512 KB)
#define WB_GST  ((size_t)220725248) // f32[64*4*64] x4: gsum1p,gsq1p,gsum2p,gsq2p (256 KB)

__device__ __forceinline__ float us2f(unsigned short u) { return __uint_as_float(((unsigned)u) << 16); }
__device__ __forceinline__ unsigned short f2bu(float f) {
  bf16 h = __float2bfloat16(f);
  return *(unsigned short*)&h;
}

// ------- 1. merged pre-pass: blocks [0,256) = xT + out:=x copy;
//            blocks [256,512) = maxpool8x8 + wprep + zero vis/vmax ---------
__global__ __launch_bounds__(256) void k_pre(const float* __restrict__ x,
                                             const float* __restrict__ mask,
                                             const float* __restrict__ w1,
                                             const float* __restrict__ w2,
                                             const float* __restrict__ fw1,
                                             const float* __restrict__ fw2,
                                             const float* __restrict__ fwf,
                                             float* __restrict__ outp,
                                             unsigned short* __restrict__ xt,
                                             unsigned char* __restrict__ mfl,
                                             float* __restrict__ vis,
                                             unsigned int* __restrict__ vmaxb,
                                             unsigned short* __restrict__ wT1,
                                             unsigned short* __restrict__ wT2,
                                             unsigned short* __restrict__ wfb) {
  __shared__ float lx[64][65];
  int t = threadIdx.x;
  if (blockIdx.x < 256) {
    int b = blockIdx.x >> 6, p0 = (blockIdx.x & 63) * 64;
    const float* xb = x + (size_t)b * CC * NN + p0;
    float* ob = outp + (size_t)b * CC * NN + p0;
    for (int idx = t; idx < 4096; idx += 256) {
      int c = idx >> 6, j = idx & 63;
      float v = xb[c * NN + j];
      lx[j][c] = v;
      ob[c * NN + j] = v;          // fg pixels overwritten later by fusion
    }
    __syncthreads();
    unsigned short* xo = xt + ((size_t)b * NN + p0) * 64;
    for (int idx = t; idx < 2048; idx += 256) {
      int j = idx >> 5, c2 = (idx & 31) * 2;
      ushort2 w2v;
      w2v.x = f2bu(lx[j][c2]);
      w2v.y = f2bu(lx[j][c2 + 1]);
      *(ushort2*)&xo[j * 64 + c2] = w2v;
    }
  } else {
    int g = (blockIdx.x - 256) * 256 + t;          // < 65536
    int o = g >> 2, sub = g & 3;
    int b = o >> 12, p = o & 4095;
    int py = p >> 6, px = p & 63;
    const float* mb = mask + (size_t)b * MH * MW + (py * 8 + sub * 2) * MW + px * 8;
    float mx = 0.f;
    #pragma unroll
    for (int dy = 0; dy < 2; ++dy) {
      const float4* r4 = (const float4*)(mb + dy * MW);
      float4 a = r4[0], c = r4[1];
      mx = fmaxf(mx, fmaxf(fmaxf(a.x, a.y), fmaxf(a.z, a.w)));
      mx = fmaxf(mx, fmaxf(fmaxf(c.x, c.y), fmaxf(c.z, c.w)));
    }
    mx = fmaxf(mx, __shfl_xor(mx, 1));
    mx = fmaxf(mx, __shfl_xor(mx, 2));
    if (sub == 0) {
      mfl[o] = (mx > 0.f) ? 1 : 0;
      vis[o] = 0.f;
    }
    if (g == 0) vmaxb[0] = 0u;
    if (g < 36864) {
      int tap = g >> 12;
      int rem = g & 4095;
      int co = rem >> 6, ci = rem & 63;
      int src = (co * 64 + ci) * 9 + tap;
      wT1[g] = f2bu(w1[src]);
      wT2[g] = f2bu(w2[src]);
    } else if (g < 57344) {
      int j2 = g - 36864;
      if (j2 < 8192)       wfb[j2] = f2bu(fw1[j2]);                 // w1b
      else if (j2 < 12288) wfb[j2] = f2bu(fw2[j2 - 8192]);          // w2b
      else                 wfb[j2] = f2bu(fwf[j2 - 12288]);         // wfb
    }
  }
}

// -------- 2. MERGED: conv1 (blocks x<64) + fg/bg compaction (x==64) --------
__global__ __launch_bounds__(256) void k_conv1c(const unsigned short* __restrict__ src,
                                                const unsigned short* __restrict__ wT,
                                                unsigned short* __restrict__ dst,
                                                float* __restrict__ gsump,
                                                float* __restrict__ gsqp,
                                                const unsigned char* __restrict__ mfl,
                                                int* __restrict__ qidx, int* __restrict__ kidx,
                                                int* __restrict__ nq, int* __restrict__ nk) {
  __shared__ unsigned short bx[198 * LS];   // 28.5 KB
  __shared__ unsigned char lm[4096];        // 4 KB (compact branch)
  int b = blockIdx.y;
  int t = threadIdx.x;
  if (blockIdx.x == 64) {
    // ---- compaction for batch b ----
    *(uint4*)&lm[t * 16] = *(const uint4*)&mfl[b * NN + t * 16];
    __syncthreads();
    if (t >= 64) return;
    int lane = t;
    int qb = 0, kb = 0;
    #pragma unroll
    for (int it = 0; it < 64; ++it) {
      int p = it * 64 + lane;
      bool f = lm[p] != 0;
      unsigned long long bal = __ballot(f);
      int before = __popcll(bal & ((1ULL << lane) - 1ULL));
      if (f)  qidx[b * NN + qb + before] = p;
      if (!f) kidx[b * NN + kb + (lane - before)] = p;
      int cnt = __popcll(bal);
      qb += cnt; kb += 64 - cnt;
    }
    if (lane == 0) { nq[b] = qb; nk[b] = kb; }
    return;
  }
  // ---- conv1 (no input norm) for row r ----
  int r = blockIdx.x;              // image row 0..63
  const unsigned short* sb = src + (size_t)b * NN * 64;
  for (int idx = t; idx < 198 * 8; idx += 256) {
    int row = idx >> 3, c8 = (idx & 7) * 8;
    int dy = row / 66;
    int cx = row - dy * 66 - 1;
    int rr = r + dy - 1;
    uint4 v = make_uint4(0u, 0u, 0u, 0u);
    if ((unsigned)rr < 64u && (unsigned)cx < 64u)
      v = *(const uint4*)(sb + ((size_t)(rr * 64 + cx)) * 64 + c8);
    *(uint4*)&bx[row * LS + c8] = v;
  }
  __syncthreads();
  int lane = t & 63;
  int quad = lane >> 4, col = lane & 15;
  int qw = (t >> 6) * 16;          // co strip
  f32x4 acc[4] = {{0.f,0.f,0.f,0.f},{0.f,0.f,0.f,0.f},{0.f,0.f,0.f,0.f},{0.f,0.f,0.f,0.f}};
  #pragma unroll
  for (int tap = 0; tap < 9; ++tap) {
    int dy = tap / 3, dx = tap - dy * 3 - 1;
    const unsigned short* wrow = wT + ((size_t)tap * 64 + qw + col) * 64;
    short8 a0 = *(const short8*)(wrow + quad * 8);
    short8 a1 = *(const short8*)(wrow + 32 + quad * 8);
    int rbase = dy * 66 + dx + 1;
    #pragma unroll
    for (int nt = 0; nt < 4; ++nt) {
      int row = rbase + nt * 16 + col;
      short8 b0 = *(const short8*)&bx[row * LS + quad * 8];
      short8 b1 = *(const short8*)&bx[row * LS + 32 + quad * 8];
      acc[nt] = __builtin_amdgcn_mfma_f32_16x16x32_bf16(a0, b0, acc[nt], 0, 0, 0);
      acc[nt] = __builtin_amdgcn_mfma_f32_16x16x32_bf16(a1, b1, acc[nt], 0, 0, 0);
    }
  }
  #pragma unroll
  for (int rr = 0; rr < 4; ++rr) {
    float s1 = acc[0][rr] + acc[1][rr] + acc[2][rr] + acc[3][rr];
    float s2 = acc[0][rr]*acc[0][rr] + acc[1][rr]*acc[1][rr]
             + acc[2][rr]*acc[2][rr] + acc[3][rr]*acc[3][rr];
    s1 += __shfl_xor(s1, 1); s2 += __shfl_xor(s2, 1);
    s1 += __shfl_xor(s1, 2); s2 += __shfl_xor(s2, 2);
    s1 += __shfl_xor(s1, 4); s2 += __shfl_xor(s2, 4);
    s1 += __shfl_xor(s1, 8); s2 += __shfl_xor(s2, 8);
    if (col == 0) {
      int co = qw + quad * 4 + rr;
      gsump[((size_t)r * BB + b) * 64 + co] = s1;
      gsqp [((size_t)r * BB + b) * 64 + co] = s2;
    }
  }
  __syncthreads();
  #pragma unroll
  for (int nt = 0; nt < 4; ++nt)
    #pragma unroll
    for (int rr = 0; rr < 4; ++rr)
      bx[(nt * 16 + col) * LS + qw + quad * 4 + rr] = f2bu(acc[nt][rr]);
  __syncthreads();
  unsigned short* db = dst + ((size_t)b * NN + r * 64) * 64;
  for (int idx = t; idx < 512; idx += 256) {
    int px = idx >> 3, c8 = (idx & 7) * 8;
    *(uint4*)(db + (size_t)px * 64 + c8) = *(const uint4*)&bx[px * LS + c8];
  }
}

// -------- 3. MFMA conv3x3(pad1), input normalized (conv2) ------------------
__global__ __launch_bounds__(256) void k_convm2(const unsigned short* __restrict__ src,
                                                const unsigned short* __restrict__ wT,
                                                const float* __restrict__ insum,
                                                const float* __restrict__ insq,
                                                unsigned short* __restrict__ dst,
                                                float* __restrict__ gsump,
                                                float* __restrict__ gsqp) {
  int b = blockIdx.y;
  int r = blockIdx.x;              // image row 0..63
  __shared__ unsigned short bx[198 * LS];   // 28.5 KB
  __shared__ float nmean[64], ninv[64];
  int t = threadIdx.x;
  if (t < 64) {
    float s = 0.f, s2v = 0.f;
    #pragma unroll 8
    for (int r2 = 0; r2 < 64; ++r2) {
      s   += insum[((size_t)r2 * BB + b) * 64 + t];
      s2v += insq [((size_t)r2 * BB + b) * 64 + t];
    }
    float m = s * (1.f / NN);
    float v = fmaxf(s2v * (1.f / NN) - m * m, 0.f);
    nmean[t] = m; ninv[t] = rsqrtf(v + 1e-5f);
  }
  __syncthreads();
  const unsigned short* sb = src + (size_t)b * NN * 64;
  for (int idx = t; idx < 198 * 8; idx += 256) {
    int row = idx >> 3, c8 = (idx & 7) * 8;
    int dy = row / 66;
    int cx = row - dy * 66 - 1;
    int rr = r + dy - 1;
    uint4 v = make_uint4(0u, 0u, 0u, 0u);
    if ((unsigned)rr < 64u && (unsigned)cx < 64u) {
      v = *(const uint4*)(sb + ((size_t)(rr * 64 + cx)) * 64 + c8);
      unsigned short* e = (unsigned short*)&v;
      #pragma unroll
      for (int j = 0; j < 8; ++j)
        e[j] = f2bu(fmaxf((us2f(e[j]) - nmean[c8 + j]) * ninv[c8 + j], 0.f));
    }
    *(uint4*)&bx[row * LS + c8] = v;
  }
  __syncthreads();
  int lane = t & 63;
  int quad = lane >> 4, col = lane & 15;
  int qw = (t >> 6) * 16;          // co strip
  f32x4 acc[4] = {{0.f,0.f,0.f,0.f},{0.f,0.f,0.f,0.f},{0.f,0.f,0.f,0.f},{0.f,0.f,0.f,0.f}};
  #pragma unroll
  for (int tap = 0; tap < 9; ++tap) {
    int dy = tap / 3, dx = tap - dy * 3 - 1;
    const unsigned short* wrow = wT + ((size_t)tap * 64 + qw + col) * 64;
    short8 a0 = *(const short8*)(wrow + quad * 8);
    short8 a1 = *(const short8*)(wrow + 32 + quad * 8);
    int rbase = dy * 66 + dx + 1;
    #pragma unroll
    for (int nt = 0; nt < 4; ++nt) {
      int row = rbase + nt * 16 + col;
      short8 b0 = *(const short8*)&bx[row * LS + quad * 8];
      short8 b1 = *(const short8*)&bx[row * LS + 32 + quad * 8];
      acc[nt] = __builtin_amdgcn_mfma_f32_16x16x32_bf16(a0, b0, acc[nt], 0, 0, 0);
      acc[nt] = __builtin_amdgcn_mfma_f32_16x16x32_bf16(a1, b1, acc[nt], 0, 0, 0);
    }
  }
  #pragma unroll
  for (int rr = 0; rr < 4; ++rr) {
    float s1 = acc[0][rr] + acc[1][rr] + acc[2][rr] + acc[3][rr];
    float s2 = acc[0][rr]*acc[0][rr] + acc[1][rr]*acc[1][rr]
             + acc[2][rr]*acc[2][rr] + acc[3][rr]*acc[3][rr];
    s1 += __shfl_xor(s1, 1); s2 += __shfl_xor(s2, 1);
    s1 += __shfl_xor(s1, 2); s2 += __shfl_xor(s2, 2);
    s1 += __shfl_xor(s1, 4); s2 += __shfl_xor(s2, 4);
    s1 += __shfl_xor(s1, 8); s2 += __shfl_xor(s2, 8);
    if (col == 0) {
      int co = qw + quad * 4 + rr;
      gsump[((size_t)r * BB + b) * 64 + co] = s1;
      gsqp [((size_t)r * BB + b) * 64 + co] = s2;
    }
  }
  __syncthreads();
  #pragma unroll
  for (int nt = 0; nt < 4; ++nt)
    #pragma unroll
    for (int rr = 0; rr < 4; ++rr)
      bx[(nt * 16 + col) * LS + qw + quad * 4 + rr] = f2bu(acc[nt][rr]);
  __syncthreads();
  unsigned short* db = dst + ((size_t)b * NN + r * 64) * 64;
  for (int idx = t; idx < 512; idx += 256) {
    int px = idx >> 3, c8 = (idx & 7) * 8;
    *(uint4*)(db + (size_t)px * 64 + c8) = *(const uint4*)&bx[px * LS + c8];
  }
}

// -------- 4. FUSED knorm+gath: normalized dense kc/qc + transposed vt ------
__global__ __launch_bounds__(256) void k_gath(const unsigned short* __restrict__ kxt,
                                              const unsigned short* __restrict__ xt,
                                              const int* __restrict__ qidx, const int* __restrict__ kidx,
                                              const int* __restrict__ nqv, const int* __restrict__ nkv,
                                              const float* __restrict__ gsump,
                                              const float* __restrict__ gsqp,
                                              unsigned short* __restrict__ kc,
                                              unsigned short* __restrict__ vt,
                                              unsigned short* __restrict__ qc) {
  int b = blockIdx.y;
  int j0 = blockIdx.x * 64;
  int nqb = nqv[b], nkb = nkv[b];
  int NKP = (nkb + 63) & ~63, NQP = (nqb + 63) & ~63;
  bool dok = j0 < NKP, doq = j0 < NQP;
  if (!dok && !doq) return;
  __shared__ int li[128];
  __shared__ unsigned short tv[64 * LS];    // V tile for transpose, 9.2 KB
  __shared__ float m2[64], i2[64];
  int t = threadIdx.x;
  if (t < 64) li[t] = (j0 + t < nkb) ? kidx[b * NN + j0 + t] : -1;
  if (t >= 64 && t < 128) li[t] = (j0 + (t - 64) < nqb) ? qidx[b * NN + j0 + (t - 64)] : -1;
  if (t >= 128 && t < 192) {
    int c = t - 128;
    float s = 0.f, s2v = 0.f;
    #pragma unroll 8
    for (int r2 = 0; r2 < 64; ++r2) {
      s   += gsump[((size_t)r2 * BB + b) * 64 + c];
      s2v += gsqp [((size_t)r2 * BB + b) * 64 + c];
    }
    float m = s * (1.f / NN);
    float v = fmaxf(s2v * (1.f / NN) - m * m, 0.f);
    m2[c] = m; i2[c] = rsqrtf(v + 1e-5f);
  }
  __syncthreads();
  const unsigned short* kxb = kxt + (size_t)b * NN * 64;
  const unsigned short* xtb = xt + (size_t)b * NN * 64;
  uint4 z = make_uint4(0u, 0u, 0u, 0u);
  for (int idx = t; idx < 512; idx += 256) {
    int row = idx >> 3, c8 = (idx & 7) * 8;
    size_t dsto = ((size_t)b * NN + j0 + row) * 64 + c8;
    if (dok) {
      int sk = li[row];
      uint4 ko = z;
      if (sk >= 0) {
        uint4 kv = *(const uint4*)(kxb + (size_t)sk * 64 + c8);
        uint4 xv = *(const uint4*)(xtb + (size_t)sk * 64 + c8);
        const unsigned short* ke = (const unsigned short*)&kv;
        const unsigned short* xe = (const unsigned short*)&xv;
        float f[8]; float ss = 0.f;
        #pragma unroll
        for (int j = 0; j < 8; ++j) {
          float v = fmaxf((us2f(ke[j]) - m2[c8 + j]) * i2[c8 + j] + us2f(xe[j]), 0.f);
          f[j] = v; ss += v * v;
        }
        ss += __shfl_xor(ss, 1); ss += __shfl_xor(ss, 2); ss += __shfl_xor(ss, 4);
        float inv = 1.f / (sqrtf(ss) + 1e-8f);
        unsigned short* oe = (unsigned short*)&ko;
        #pragma unroll
        for (int j = 0; j < 8; ++j) oe[j] = f2bu(f[j] * inv);
        *(uint4*)&tv[row * LS + c8] = xv;
      } else {
        float ss = 0.f;
        ss += __shfl_xor(ss, 1); ss += __shfl_xor(ss, 2); ss += __shfl_xor(ss, 4);
        *(uint4*)&tv[row * LS + c8] = z;
      }
      *(uint4*)(kc + dsto) = ko;
    }
    if (doq) {
      int sq = li[64 + row];
      uint4 qo = z;
      if (sq >= 0) {
        uint4 kv = *(const uint4*)(kxb + (size_t)sq * 64 + c8);
        uint4 xv = *(const uint4*)(xtb + (size_t)sq * 64 + c8);
        const unsigned short* ke = (const unsigned short*)&kv;
        const unsigned short* xe = (const unsigned short*)&xv;
        float f[8]; float ss = 0.f;
        #pragma unroll
        for (int j = 0; j < 8; ++j) {
          float v = fmaxf((us2f(ke[j]) - m2[c8 + j]) * i2[c8 + j] + us2f(xe[j]), 0.f);
          f[j] = v; ss += v * v;
        }
        ss += __shfl_xor(ss, 1); ss += __shfl_xor(ss, 2); ss += __shfl_xor(ss, 4);
        float inv = 1.f / (sqrtf(ss) + 1e-8f);
        unsigned short* oe = (unsigned short*)&qo;
        #pragma unroll
        for (int j = 0; j < 8; ++j) oe[j] = f2bu(f[j] * inv);
      } else {
        float ss = 0.f;
        ss += __shfl_xor(ss, 1); ss += __shfl_xor(ss, 2); ss += __shfl_xor(ss, 4);
      }
      *(uint4*)(qc + dsto) = qo;
    }
  }
  __syncthreads();
  if (!dok) return;
  for (int idx = t; idx < 512; idx += 256) {
    int c = idx >> 3, k8 = (idx & 7) * 8;
    unsigned short vals[8];
    #pragma unroll
    for (int j = 0; j < 8; ++j) vals[j] = tv[(k8 + j) * LS + c];
    *(uint4*)(vt + (size_t)b * 262144 + (size_t)c * 4096 + j0 + k8) = *(const uint4*)&vals[0];
  }
}

// -------- 5. attention pass 1: 4 independent waves, zero barriers,
//            NPARTS=4 (each wave ~8 tiles, amortized prologue) --------------
__global__ __launch_bounds__(256) void k_att1(const unsigned short* __restrict__ kc,
                                              const unsigned short* __restrict__ vt,
                                              const unsigned short* __restrict__ qc,
                                              const int* __restrict__ nqv, const int* __restrict__ nkv,
                                              unsigned short* __restrict__ afc_part,
                                              float* __restrict__ den_part,
                                              unsigned short* __restrict__ eg) {
  __shared__ unsigned short leb[4][32 * LS];   // per-wave slices, 18.4 KB
  int b = blockIdx.y;
  int nqb = nqv[b], nkb = nkv[b];
  int t = threadIdx.x;
  int wave = t >> 6, lane = t & 63;
  int part = blockIdx.x & (NPARTS - 1);
  int q0 = ((blockIdx.x / NPARTS) * 4 + wave) * 32;   // 32 q rows per wave
  if (q0 >= nqb) return;                          // wave-uniform; no barriers
  int ntiles = (nkb + 63) >> 6;
  int nt_blk = (part < ntiles) ? ((ntiles - part + NPARTS - 1) / NPARTS) : 0;
  int NKP = (nkb + 63) & ~63;                     // E row stride (elements)
  unsigned short* le = leb[wave];
  int l31 = lane & 31, lhi = lane >> 5;
  const unsigned short* kcb = kc + (size_t)b * NN * 64;
  const unsigned short* vtb = vt + (size_t)b * 262144;
  const unsigned short* qcb = qc + (size_t)b * NN * 64;
  unsigned short* egb = eg + (size_t)b * EB_ELEM;
  unsigned short* afcp = afc_part + ((size_t)b * NN) * (NPARTS * 64);
  float* denp = den_part + ((size_t)b * NN) * NDEN;
  short8 aq[4];
  #pragma unroll
  for (int ks = 0; ks < 4; ++ks)
    aq[ks] = *(const short8*)(qcb + (size_t)(q0 + l31) * 64 + ks * 16 + lhi * 8);
  f32x16 pv0, pv1, dsum;
  #pragma unroll
  for (int i = 0; i < 16; ++i) { pv0[i] = 0.f; pv1[i] = 0.f; dsum[i] = 0.f; }
  for (int it = 0; it < nt_blk; ++it) {
    int j0 = (part + it * NPARTS) * 64;
    #pragma unroll
    for (int kh = 0; kh < 2; ++kh) {
      f32x16 s;
      #pragma unroll
      for (int i = 0; i < 16; ++i) s[i] = 0.f;
      const unsigned short* krow = kcb + (size_t)(j0 + kh * 32 + l31) * 64 + lhi * 8;
      #pragma unroll
      for (int ks = 0; ks < 4; ++ks) {
        short8 bk = *(const short8*)(krow + ks * 16);
        s = __builtin_amdgcn_mfma_f32_32x32x16_bf16(aq[ks], bk, s, 0, 0, 0);
      }
      bool kval = (j0 + kh * 32 + l31) < nkb;
      #pragma unroll
      for (int reg = 0; reg < 16; ++reg) {
        float e = kval ? __expf(20.f * s[reg]) : 0.f;
        dsum[reg] += e;
        int row = (reg & 3) + 8 * (reg >> 2) + 4 * lhi;
        le[row * LS + kh * 32 + l31] = f2bu(e);
      }
    }
    #pragma unroll
    for (int ks = 0; ks < 4; ++ks) {
      short8 a = *(const short8*)&le[l31 * LS + ks * 16 + lhi * 8];
      short8 bv0 = *(const short8*)(vtb + (size_t)l31 * 4096 + j0 + ks * 16 + lhi * 8);
      short8 bv1 = *(const short8*)(vtb + (size_t)(32 + l31) * 4096 + j0 + ks * 16 + lhi * 8);
      pv0 = __builtin_amdgcn_mfma_f32_32x32x16_bf16(a, bv0, pv0, 0, 0, 0);
      pv1 = __builtin_amdgcn_mfma_f32_32x32x16_bf16(a, bv1, pv1, 0, 0, 0);
    }
    #pragma unroll
    for (int sub = 0; sub < 4; ++sub) {
      int idx = sub * 64 + lane;
      int q = idx >> 3, cc8 = (idx & 7) * 8;
      if (q0 + q < nqb)
        *(uint4*)(egb + (size_t)(q0 + q) * NKP + j0 + cc8) = *(const uint4*)&le[q * LS + cc8];
    }
  }
  #pragma unroll
  for (int reg = 0; reg < 16; ++reg) {
    float v = dsum[reg];
    v += __shfl_xor(v, 1); v += __shfl_xor(v, 2); v += __shfl_xor(v, 4);
    v += __shfl_xor(v, 8); v += __shfl_xor(v, 16);
    int row = (reg & 3) + 8 * (reg >> 2) + 4 * lhi;
    int qq = q0 + row;
    if (l31 == 0 && qq < nqb) denp[(size_t)qq * NDEN + part] = v;
  }
  #pragma unroll
  for (int reg = 0; reg < 16; ++reg) {
    int row = (reg & 3) + 8 * (reg >> 2) + 4 * lhi;
    int qq = q0 + row;
    if (qq < nqb) {
      unsigned short* ap = afcp + ((size_t)qq * NPARTS + part) * 64;
      ap[l31]      = f2bu(pv0[reg]);
      ap[32 + l31] = f2bu(pv1[reg]);
    }
  }
}

// -------- 6. MERGED post: blocks x<128 = vis column-sum; x>=128 = fusion ---
#define FS 136            // pxa row stride (bf16)
__global__ __launch_bounds__(256) void k_post(const unsigned short* __restrict__ eg,
                                              const float* __restrict__ den_part,
                                              const int* __restrict__ nqv, const int* __restrict__ nkv,
                                              float* __restrict__ visp,
                                              const unsigned short* __restrict__ xt,
                                              const unsigned short* __restrict__ afc_part,
                                              const int* __restrict__ qidx,
                                              const unsigned short* __restrict__ wall,
                                              const float* __restrict__ b2,
                                              float* __restrict__ outp) {
  __shared__ unsigned short pxa[64 * FS];   // 17.4 KB (fusion)
  __shared__ unsigned short f1s[64 * LS];   // 9.2 KB (fusion)
  __shared__ int qpl[64];
  __shared__ float wd[256];                 // 1 KB (vis)
  int b = blockIdx.y;
  int nqb = nqv[b], nkb = nkv[b];
  int t = threadIdx.x;
  if (blockIdx.x < 128) {
    // ---- vis column-sum ----
    int k0 = (blockIdx.x & 15) * 256;
    if (k0 >= nkb) return;
    int NKP = (nkb + 63) & ~63;
    int qpart = blockIdx.x >> 4;
    int qbeg = (qpart * nqb) >> 3;
    int qend = ((qpart + 1) * nqb) >> 3;
    int k = k0 + t;
    const unsigned short* eb = eg + (size_t)b * EB_ELEM;
    float acc = 0.f;
    for (int qc = qbeg; qc < qend; qc += 256) {
      __syncthreads();
      int qq = qc + t;
      float d = 0.f;
      if (qq < qend) {
        const float4* dp = (const float4*)(den_part + ((size_t)b * NN + qq) * NDEN);
        float4 a0 = dp[0];
        d = (a0.x + a0.y) + (a0.z + a0.w);
      }
      wd[t] = (d > 0.f) ? 1.f / d : 0.f;
      __syncthreads();
      int lim = min(256, qend - qc);
      if (k < nkb) {
        const unsigned short* ep = eb + (size_t)qc * NKP + k;
        int j = 0;
        for (; j + 8 <= lim; j += 8) {
          #pragma unroll
          for (int u = 0; u < 8; ++u)
            acc += us2f(ep[(size_t)(j + u) * NKP]) * wd[j + u];
        }
        for (; j < lim; ++j)
          acc += us2f(ep[(size_t)j * NKP]) * wd[j];
      }
    }
    if (k < nkb) visp[((size_t)qpart * BB + b) * NN + k] = acc;
    return;
  }
  // ---- fusion epilogue ----
  int q0 = (blockIdx.x - 128) * 64;
  if (q0 >= nqb) return;
  int lane = t & 63;
  int quad = lane >> 4, col = lane & 15;
  int cb = (t >> 6) * 16;                   // wave's co strip
  const int* qix = qidx + b * NN;
  const unsigned short* xtb = xt + (size_t)b * NN * 64;
  const unsigned short* w1b = wall;
  const unsigned short* w2b = wall + 8192;
  const unsigned short* wfb = wall + 12288;
  short8 a1[4], a2[2], af[4];
  #pragma unroll
  for (int kt = 0; kt < 4; ++kt) {
    a1[kt] = *(const short8*)&w1b[(cb + col) * 128 + kt * 32 + quad * 8];
    af[kt] = *(const short8*)&wfb[(cb + col) * 128 + kt * 32 + quad * 8];
  }
  #pragma unroll
  for (int kt = 0; kt < 2; ++kt)
    a2[kt] = *(const short8*)&w2b[(cb + col) * 64 + kt * 32 + quad * 8];
  float b2v[4];
  #pragma unroll
  for (int r = 0; r < 4; ++r) b2v[r] = b2[cb + quad * 4 + r];
  if (t < 64) qpl[t] = (q0 + t < nqb) ? qix[q0 + t] : -1;
  for (int idx = t; idx < 512; idx += 256) {
    int q = idx >> 3, c8 = (idx & 7) * 8;
    int qq = q0 + q;
    uint4 pv = make_uint4(0u, 0u, 0u, 0u);
    unsigned short pa8[8] = {0, 0, 0, 0, 0, 0, 0, 0};
    if (qq < nqb) {
      int qp = qix[qq];
      pv = *(const uint4*)(xtb + (size_t)qp * 64 + c8);
      const float* db = den_part + ((size_t)b * NN + qq) * NDEN;
      float d = 0.f;
      #pragma unroll
      for (int p2 = 0; p2 < NDEN; ++p2) d += db[p2];
      float av[8];
      #pragma unroll
      for (int j = 0; j < 8; ++j) av[j] = 0.f;
      const unsigned short* ab = afc_part + ((size_t)b * NN + qq) * (NPARTS * 64) + c8;
      #pragma unroll
      for (int p2 = 0; p2 < NPARTS; ++p2) {
        const uint4 u = *(const uint4*)(ab + p2 * 64);
        const unsigned short* e8 = (const unsigned short*)&u;
        #pragma unroll
        for (int j = 0; j < 8; ++j) av[j] += us2f(e8[j]);
      }
      float invd = (d > 0.f) ? 1.f / d : 0.f;
      #pragma unroll
      for (int j = 0; j < 8; ++j) pa8[j] = f2bu(av[j] * invd);
    }
    *(uint4*)&pxa[q * FS + c8] = pv;
    *(uint4*)&pxa[q * FS + 64 + c8] = *(const uint4*)&pa8[0];
  }
  __syncthreads();
  #pragma unroll
  for (int qt = 0; qt < 4; ++qt) {
    f32x4 acc = {0.f, 0.f, 0.f, 0.f};
    #pragma unroll
    for (int kt = 0; kt < 4; ++kt) {
      short8 bfrag = *(const short8*)&pxa[(qt * 16 + col) * FS + kt * 32 + quad * 8];
      acc = __builtin_amdgcn_mfma_f32_16x16x32_bf16(a1[kt], bfrag, acc, 0, 0, 0);
    }
    #pragma unroll
    for (int r = 0; r < 4; ++r)
      f1s[(qt * 16 + col) * LS + cb + quad * 4 + r] = f2bu(acc[r]);
  }
  __syncthreads();
  #pragma unroll
  for (int qt = 0; qt < 4; ++qt) {
    f32x4 acc = {0.f, 0.f, 0.f, 0.f};
    #pragma unroll
    for (int kt = 0; kt < 2; ++kt) {
      short8 bfrag = *(const short8*)&f1s[(qt * 16 + col) * LS + kt * 32 + quad * 8];
      acc = __builtin_amdgcn_mfma_f32_16x16x32_bf16(a2[kt], bfrag, acc, 0, 0, 0);
    }
    #pragma unroll
    for (int r = 0; r < 4; ++r) {
      float sg = 1.f / (1.f + __expf(-(acc[r] + b2v[r])));
      int addr = (qt * 16 + col) * FS + 64 + cb + quad * 4 + r;
      pxa[addr] = f2bu(us2f(pxa[addr]) * (1.f - sg));
    }
  }
  __syncthreads();
  #pragma unroll
  for (int qt = 0; qt < 4; ++qt) {
    f32x4 acc = {0.f, 0.f, 0.f, 0.f};
    #pragma unroll
    for (int kt = 0; kt < 4; ++kt) {
      short8 bfrag = *(const short8*)&pxa[(qt * 16 + col) * FS + kt * 32 + quad * 8];
      acc = __builtin_amdgcn_mfma_f32_16x16x32_bf16(af[kt], bfrag, acc, 0, 0, 0);
    }
    int qp = qpl[qt * 16 + col];
    if (qp >= 0) {
      #pragma unroll
      for (int r = 0; r < 4; ++r)
        outp[((size_t)b * CC + cb + quad * 4 + r) * NN + qp] = acc[r];
    }
  }
}

// -------- 7a. sum vis partials, scatter to pixel grid, global max ----------
__global__ __launch_bounds__(256) void k_vmax(const float* __restrict__ visp,
                                              const int* __restrict__ kidx,
                                              const int* __restrict__ nkv,
                                              float* __restrict__ vis,
                                              unsigned int* __restrict__ vmaxb) {
  int i = blockIdx.x * 256 + threadIdx.x;    // < 16384
  int b = i >> 12, k = i & 4095;
  float v = 0.f;
  if (k < nkv[b]) {
    #pragma unroll
    for (int p2 = 0; p2 < 8; ++p2) v += visp[((size_t)p2 * BB + b) * NN + k];
    vis[b * NN + kidx[b * NN + k]] = v;
  }
  #pragma unroll
  for (int off = 32; off > 0; off >>= 1) v = fmaxf(v, __shfl_down(v, off));
  if ((threadIdx.x & 63) == 0) atomicMax(vmaxb, __float_as_uint(v));
}

// -------- 7b. x8 nearest upsample + normalize (float4 stores) --------------
__global__ __launch_bounds__(256) void k_upsample(const float* __restrict__ vis,
                                                  const unsigned int* __restrict__ vmaxb,
                                                  float* __restrict__ out2) {
  int i4 = blockIdx.x * 256 + threadIdx.x;   // < 262144 float4s
  int b = i4 >> 16;
  int rem = i4 & 65535;
  int y = rem >> 7, x4 = (rem & 127) * 4;
  float vm = __uint_as_float(vmaxb[0]);
  if (!(vm > 0.f)) vm = 1.f;
  float v = vis[b * NN + (y >> 3) * 64 + (x4 >> 3)] / vm;
  ((float4*)out2)[i4] = make_float4(v, v, v, v);
}

extern "C" void kernel_launch(void* const* d_in, const int* in_sizes, int n_in,
                              void* d_out, int out_size, void* d_ws, size_t ws_size,
                              hipStream_t stream) {
  const float* x    = (const float*)d_in[0];
  const float* mask = (const float*)d_in[1];
  const float* w1   = (const float*)d_in[2];
  const float* w2c  = (const float*)d_in[3];
  const float* fsw1 = (const float*)d_in[4];
  const float* fsw2 = (const float*)d_in[5];
  const float* fsb2 = (const float*)d_in[6];
  const float* fswf = (const float*)d_in[7];
  float* out = (float*)d_out;
  char* wsb = (char*)d_ws;

  float* vis = (float*)(wsb + WB_VIS);
  int* qidx  = (int*)(wsb + WB_QIX);
  int* kidx  = (int*)(wsb + WB_KIX);
  unsigned char* mfl = (unsigned char*)(wsb + WB_MFL);
  int* nq = (int*)(wsb + WB_CNT);
  int* nk = nq + 4;
  unsigned int* vmaxb = (unsigned int*)(nq + 8);
  unsigned short* wT1 = (unsigned short*)(wsb + WB_WT1);
  unsigned short* wT2 = (unsigned short*)(wsb + WB_WT2);
  unsigned short* wall = (unsigned short*)(wsb + WB_WFB);
  unsigned short* y1t = (unsigned short*)(wsb + WB_Y1T);   // conv scratch
  unsigned short* xt  = (unsigned short*)(wsb + WB_XT);
  unsigned short* kxt = (unsigned short*)(wsb + WB_KXT);
  unsigned short* kc  = (unsigned short*)(wsb + WB_KC);
  unsigned short* vt  = (unsigned short*)(wsb + WB_VT);
  unsigned short* qc  = (unsigned short*)(wsb + WB_QC);
  unsigned short* eg  = (unsigned short*)(wsb + WB_E);
  unsigned short* afc_part = (unsigned short*)(wsb + WB_AFCP);
  float* den_part = (float*)(wsb + WB_DENP);
  float* visp     = (float*)(wsb + WB_VISP);
  float* gsum1p = (float*)(wsb + WB_GST);
  float* gsq1p  = (float*)(wsb + WB_GST + 65536);
  float* gsum2p = (float*)(wsb + WB_GST + 131072);
  float* gsq2p  = (float*)(wsb + WB_GST + 196608);

  k_pre<<<512, 256, 0, stream>>>(x, mask, w1, w2c, fsw1, fsw2, fswf,
                                 out, xt, mfl, vis, vmaxb, wT1, wT2, wall);
  k_conv1c<<<dim3(65, BB), 256, 0, stream>>>(xt, wT1, y1t, gsum1p, gsq1p,
                                             mfl, qidx, kidx, nq, nk);
  k_convm2<<<dim3(64, BB), 256, 0, stream>>>(y1t, wT2, gsum1p, gsq1p, kxt, gsum2p, gsq2p);
  k_gath<<<dim3(64, BB), 256, 0, stream>>>(kxt, xt, qidx, kidx, nq, nk, gsum2p, gsq2p, kc, vt, qc);
  k_att1<<<dim3(32 * NPARTS, BB), 256, 0, stream>>>(kc, vt, qc, nq, nk, afc_part, den_part, eg);
  k_post<<<dim3(192, BB), 256, 0, stream>>>(eg, den_part, nq, nk, visp,
                                            xt, afc_part, qidx, wall, fsb2, out);
  k_vmax<<<64, 256, 0, stream>>>(visp, kidx, nk, vis, vmaxb);
  k_upsample<<<1024, 256, 0, stream>>>(vis, vmaxb, out + 1048576);
}

// Round 16
// 163.374 us; speedup vs baseline: 1.0314x; 1.0314x over previous
//
#include <hip/hip_runtime.h>
#include <hip/hip_bf16.h>

typedef __hip_bfloat16 bf16;
typedef __attribute__((ext_vector_type(8))) short short8;
typedef __attribute__((ext_vector_type(4))) float f32x4;
typedef __attribute__((ext_vector_type(16))) float f32x16;

#define BB 4
#define CC 64
#define NN 4096           // 64*64
#define MH 512
#define MW 512
#define LS 72             // LDS row stride in bf16 elements
#define NPARTS 16         // k-split factor in k_att1 (16 beats 4: concurrency > amortization)
#define NDEN 16           // den partial slices

// ---- workspace layout (BYTE offsets; ws is 256 MiB) ----
#define WB_Y1T  ((size_t)0)         // 4 MB scratch: y1t (bf16 conv1 raw)
#define WB_VIS  ((size_t)4259840)   // f32[4*4096] visatt (final, scatter)
#define WB_QIX  ((size_t)4325376)   // int[4*4096]
#define WB_KIX  ((size_t)4390912)   // int[4*4096]
#define WB_MFL  ((size_t)4456448)   // uchar[4*4096]
#define WB_CNT  ((size_t)4472832)   // int nq[4]; int nk[4]; uint vmaxbits
#define WB_WT1  ((size_t)4476992)   // bf16[9*64*64] wT1
#define WB_WT2  ((size_t)4550720)   // bf16[9*64*64] wT2
#define WB_WFB  ((size_t)4624448)   // bf16 w1b[8192]; w2b[4096]; wfb[8192]
#define WB_KC   ((size_t)5242880)   // bf16[4*4096*64] compacted normalized K rows (2 MiB)
#define WB_XT   ((size_t)8388608)   // bf16[4*4096*64] xt (pixel-major x)
#define WB_KXT  ((size_t)10485760)  // bf16[4*4096*64] kxt (conv2 RAW output)
#define WB_VT   ((size_t)12582912)  // bf16[4][64][4096] TRANSPOSED compacted V (2 MiB)
#define WB_QC   ((size_t)14680064)  // bf16[4*4096*64] compacted normalized Q rows (2 MiB)
#define WB_E    ((size_t)16777216)  // bf16 E cache: per-batch stride 32 MiB (128 MiB)
#define EB_ELEM ((size_t)16777216)  // E elements per batch (32 MiB / 2B)
#define WB_AFCP ((size_t)150994944) // bf16[4][4096][16][64] afc partials, q-major (32 MiB)
#define WB_DENP ((size_t)218103808) // f32[4][4096][16] den partials, q-major (1 MiB)
#define WB_VISP ((size_t)220200960) // f32[8][4][4096] vis partials (512 KB)
#define WB_GST  ((size_t)220725248) // f32[64*4*64] x4: gsum1p,gsq1p,gsum2p,gsq2p (256 KB)

__device__ __forceinline__ float us2f(unsigned short u) { return __uint_as_float(((unsigned)u) << 16); }
__device__ __forceinline__ unsigned short f2bu(float f) {
  bf16 h = __float2bfloat16(f);
  return *(unsigned short*)&h;
}

// ------- 1. merged pre-pass: blocks [0,256) = xT + out:=x copy;
//            blocks [256,512) = maxpool8x8 + wprep + zero vis/vmax ---------
__global__ __launch_bounds__(256) void k_pre(const float* __restrict__ x,
                                             const float* __restrict__ mask,
                                             const float* __restrict__ w1,
                                             const float* __restrict__ w2,
                                             const float* __restrict__ fw1,
                                             const float* __restrict__ fw2,
                                             const float* __restrict__ fwf,
                                             float* __restrict__ outp,
                                             unsigned short* __restrict__ xt,
                                             unsigned char* __restrict__ mfl,
                                             float* __restrict__ vis,
                                             unsigned int* __restrict__ vmaxb,
                                             unsigned short* __restrict__ wT1,
                                             unsigned short* __restrict__ wT2,
                                             unsigned short* __restrict__ wfb) {
  __shared__ float lx[64][65];
  int t = threadIdx.x;
  if (blockIdx.x < 256) {
    int b = blockIdx.x >> 6, p0 = (blockIdx.x & 63) * 64;
    const float* xb = x + (size_t)b * CC * NN + p0;
    float* ob = outp + (size_t)b * CC * NN + p0;
    for (int idx = t; idx < 4096; idx += 256) {
      int c = idx >> 6, j = idx & 63;
      float v = xb[c * NN + j];
      lx[j][c] = v;
      ob[c * NN + j] = v;          // fg pixels overwritten later by fusion
    }
    __syncthreads();
    unsigned short* xo = xt + ((size_t)b * NN + p0) * 64;
    for (int idx = t; idx < 2048; idx += 256) {
      int j = idx >> 5, c2 = (idx & 31) * 2;
      ushort2 w2v;
      w2v.x = f2bu(lx[j][c2]);
      w2v.y = f2bu(lx[j][c2 + 1]);
      *(ushort2*)&xo[j * 64 + c2] = w2v;
    }
  } else {
    int g = (blockIdx.x - 256) * 256 + t;          // < 65536
    int o = g >> 2, sub = g & 3;
    int b = o >> 12, p = o & 4095;
    int py = p >> 6, px = p & 63;
    const float* mb = mask + (size_t)b * MH * MW + (py * 8 + sub * 2) * MW + px * 8;
    float mx = 0.f;
    #pragma unroll
    for (int dy = 0; dy < 2; ++dy) {
      const float4* r4 = (const float4*)(mb + dy * MW);
      float4 a = r4[0], c = r4[1];
      mx = fmaxf(mx, fmaxf(fmaxf(a.x, a.y), fmaxf(a.z, a.w)));
      mx = fmaxf(mx, fmaxf(fmaxf(c.x, c.y), fmaxf(c.z, c.w)));
    }
    mx = fmaxf(mx, __shfl_xor(mx, 1));
    mx = fmaxf(mx, __shfl_xor(mx, 2));
    if (sub == 0) {
      mfl[o] = (mx > 0.f) ? 1 : 0;
      vis[o] = 0.f;
    }
    if (g == 0) vmaxb[0] = 0u;
    if (g < 36864) {
      int tap = g >> 12;
      int rem = g & 4095;
      int co = rem >> 6, ci = rem & 63;
      int src = (co * 64 + ci) * 9 + tap;
      wT1[g] = f2bu(w1[src]);
      wT2[g] = f2bu(w2[src]);
    } else if (g < 57344) {
      int j2 = g - 36864;
      if (j2 < 8192)       wfb[j2] = f2bu(fw1[j2]);                 // w1b
      else if (j2 < 12288) wfb[j2] = f2bu(fw2[j2 - 8192]);          // w2b
      else                 wfb[j2] = f2bu(fwf[j2 - 12288]);         // wfb
    }
  }
}

// -------- 2. MERGED: conv1 (blocks x<64) + fg/bg compaction (x==64) --------
__global__ __launch_bounds__(256) void k_conv1c(const unsigned short* __restrict__ src,
                                                const unsigned short* __restrict__ wT,
                                                unsigned short* __restrict__ dst,
                                                float* __restrict__ gsump,
                                                float* __restrict__ gsqp,
                                                const unsigned char* __restrict__ mfl,
                                                int* __restrict__ qidx, int* __restrict__ kidx,
                                                int* __restrict__ nq, int* __restrict__ nk) {
  __shared__ unsigned short bx[198 * LS];   // 28.5 KB
  __shared__ unsigned char lm[4096];        // 4 KB (compact branch)
  int b = blockIdx.y;
  int t = threadIdx.x;
  if (blockIdx.x == 64) {
    // ---- compaction for batch b ----
    *(uint4*)&lm[t * 16] = *(const uint4*)&mfl[b * NN + t * 16];
    __syncthreads();
    if (t >= 64) return;
    int lane = t;
    int qb = 0, kb = 0;
    #pragma unroll
    for (int it = 0; it < 64; ++it) {
      int p = it * 64 + lane;
      bool f = lm[p] != 0;
      unsigned long long bal = __ballot(f);
      int before = __popcll(bal & ((1ULL << lane) - 1ULL));
      if (f)  qidx[b * NN + qb + before] = p;
      if (!f) kidx[b * NN + kb + (lane - before)] = p;
      int cnt = __popcll(bal);
      qb += cnt; kb += 64 - cnt;
    }
    if (lane == 0) { nq[b] = qb; nk[b] = kb; }
    return;
  }
  // ---- conv1 (no input norm) for row r ----
  int r = blockIdx.x;              // image row 0..63
  const unsigned short* sb = src + (size_t)b * NN * 64;
  for (int idx = t; idx < 198 * 8; idx += 256) {
    int row = idx >> 3, c8 = (idx & 7) * 8;
    int dy = row / 66;
    int cx = row - dy * 66 - 1;
    int rr = r + dy - 1;
    uint4 v = make_uint4(0u, 0u, 0u, 0u);
    if ((unsigned)rr < 64u && (unsigned)cx < 64u)
      v = *(const uint4*)(sb + ((size_t)(rr * 64 + cx)) * 64 + c8);
    *(uint4*)&bx[row * LS + c8] = v;
  }
  __syncthreads();
  int lane = t & 63;
  int quad = lane >> 4, col = lane & 15;
  int qw = (t >> 6) * 16;          // co strip
  f32x4 acc[4] = {{0.f,0.f,0.f,0.f},{0.f,0.f,0.f,0.f},{0.f,0.f,0.f,0.f},{0.f,0.f,0.f,0.f}};
  #pragma unroll
  for (int tap = 0; tap < 9; ++tap) {
    int dy = tap / 3, dx = tap - dy * 3 - 1;
    const unsigned short* wrow = wT + ((size_t)tap * 64 + qw + col) * 64;
    short8 a0 = *(const short8*)(wrow + quad * 8);
    short8 a1 = *(const short8*)(wrow + 32 + quad * 8);
    int rbase = dy * 66 + dx + 1;
    #pragma unroll
    for (int nt = 0; nt < 4; ++nt) {
      int row = rbase + nt * 16 + col;
      short8 b0 = *(const short8*)&bx[row * LS + quad * 8];
      short8 b1 = *(const short8*)&bx[row * LS + 32 + quad * 8];
      acc[nt] = __builtin_amdgcn_mfma_f32_16x16x32_bf16(a0, b0, acc[nt], 0, 0, 0);
      acc[nt] = __builtin_amdgcn_mfma_f32_16x16x32_bf16(a1, b1, acc[nt], 0, 0, 0);
    }
  }
  #pragma unroll
  for (int rr = 0; rr < 4; ++rr) {
    float s1 = acc[0][rr] + acc[1][rr] + acc[2][rr] + acc[3][rr];
    float s2 = acc[0][rr]*acc[0][rr] + acc[1][rr]*acc[1][rr]
             + acc[2][rr]*acc[2][rr] + acc[3][rr]*acc[3][rr];
    s1 += __shfl_xor(s1, 1); s2 += __shfl_xor(s2, 1);
    s1 += __shfl_xor(s1, 2); s2 += __shfl_xor(s2, 2);
    s1 += __shfl_xor(s1, 4); s2 += __shfl_xor(s2, 4);
    s1 += __shfl_xor(s1, 8); s2 += __shfl_xor(s2, 8);
    if (col == 0) {
      int co = qw + quad * 4 + rr;
      gsump[((size_t)r * BB + b) * 64 + co] = s1;
      gsqp [((size_t)r * BB + b) * 64 + co] = s2;
    }
  }
  __syncthreads();
  #pragma unroll
  for (int nt = 0; nt < 4; ++nt)
    #pragma unroll
    for (int rr = 0; rr < 4; ++rr)
      bx[(nt * 16 + col) * LS + qw + quad * 4 + rr] = f2bu(acc[nt][rr]);
  __syncthreads();
  unsigned short* db = dst + ((size_t)b * NN + r * 64) * 64;
  for (int idx = t; idx < 512; idx += 256) {
    int px = idx >> 3, c8 = (idx & 7) * 8;
    *(uint4*)(db + (size_t)px * 64 + c8) = *(const uint4*)&bx[px * LS + c8];
  }
}

// -------- 3. MFMA conv3x3(pad1), input normalized (conv2) ------------------
__global__ __launch_bounds__(256) void k_convm2(const unsigned short* __restrict__ src,
                                                const unsigned short* __restrict__ wT,
                                                const float* __restrict__ insum,
                                                const float* __restrict__ insq,
                                                unsigned short* __restrict__ dst,
                                                float* __restrict__ gsump,
                                                float* __restrict__ gsqp) {
  int b = blockIdx.y;
  int r = blockIdx.x;              // image row 0..63
  __shared__ unsigned short bx[198 * LS];   // 28.5 KB
  __shared__ float nmean[64], ninv[64];
  int t = threadIdx.x;
  if (t < 64) {
    float s = 0.f, s2v = 0.f;
    #pragma unroll 8
    for (int r2 = 0; r2 < 64; ++r2) {
      s   += insum[((size_t)r2 * BB + b) * 64 + t];
      s2v += insq [((size_t)r2 * BB + b) * 64 + t];
    }
    float m = s * (1.f / NN);
    float v = fmaxf(s2v * (1.f / NN) - m * m, 0.f);
    nmean[t] = m; ninv[t] = rsqrtf(v + 1e-5f);
  }
  __syncthreads();
  const unsigned short* sb = src + (size_t)b * NN * 64;
  for (int idx = t; idx < 198 * 8; idx += 256) {
    int row = idx >> 3, c8 = (idx & 7) * 8;
    int dy = row / 66;
    int cx = row - dy * 66 - 1;
    int rr = r + dy - 1;
    uint4 v = make_uint4(0u, 0u, 0u, 0u);
    if ((unsigned)rr < 64u && (unsigned)cx < 64u) {
      v = *(const uint4*)(sb + ((size_t)(rr * 64 + cx)) * 64 + c8);
      unsigned short* e = (unsigned short*)&v;
      #pragma unroll
      for (int j = 0; j < 8; ++j)
        e[j] = f2bu(fmaxf((us2f(e[j]) - nmean[c8 + j]) * ninv[c8 + j], 0.f));
    }
    *(uint4*)&bx[row * LS + c8] = v;
  }
  __syncthreads();
  int lane = t & 63;
  int quad = lane >> 4, col = lane & 15;
  int qw = (t >> 6) * 16;          // co strip
  f32x4 acc[4] = {{0.f,0.f,0.f,0.f},{0.f,0.f,0.f,0.f},{0.f,0.f,0.f,0.f},{0.f,0.f,0.f,0.f}};
  #pragma unroll
  for (int tap = 0; tap < 9; ++tap) {
    int dy = tap / 3, dx = tap - dy * 3 - 1;
    const unsigned short* wrow = wT + ((size_t)tap * 64 + qw + col) * 64;
    short8 a0 = *(const short8*)(wrow + quad * 8);
    short8 a1 = *(const short8*)(wrow + 32 + quad * 8);
    int rbase = dy * 66 + dx + 1;
    #pragma unroll
    for (int nt = 0; nt < 4; ++nt) {
      int row = rbase + nt * 16 + col;
      short8 b0 = *(const short8*)&bx[row * LS + quad * 8];
      short8 b1 = *(const short8*)&bx[row * LS + 32 + quad * 8];
      acc[nt] = __builtin_amdgcn_mfma_f32_16x16x32_bf16(a0, b0, acc[nt], 0, 0, 0);
      acc[nt] = __builtin_amdgcn_mfma_f32_16x16x32_bf16(a1, b1, acc[nt], 0, 0, 0);
    }
  }
  #pragma unroll
  for (int rr = 0; rr < 4; ++rr) {
    float s1 = acc[0][rr] + acc[1][rr] + acc[2][rr] + acc[3][rr];
    float s2 = acc[0][rr]*acc[0][rr] + acc[1][rr]*acc[1][rr]
             + acc[2][rr]*acc[2][rr] + acc[3][rr]*acc[3][rr];
    s1 += __shfl_xor(s1, 1); s2 += __shfl_xor(s2, 1);
    s1 += __shfl_xor(s1, 2); s2 += __shfl_xor(s2, 2);
    s1 += __shfl_xor(s1, 4); s2 += __shfl_xor(s2, 4);
    s1 += __shfl_xor(s1, 8); s2 += __shfl_xor(s2, 8);
    if (col == 0) {
      int co = qw + quad * 4 + rr;
      gsump[((size_t)r * BB + b) * 64 + co] = s1;
      gsqp [((size_t)r * BB + b) * 64 + co] = s2;
    }
  }
  __syncthreads();
  #pragma unroll
  for (int nt = 0; nt < 4; ++nt)
    #pragma unroll
    for (int rr = 0; rr < 4; ++rr)
      bx[(nt * 16 + col) * LS + qw + quad * 4 + rr] = f2bu(acc[nt][rr]);
  __syncthreads();
  unsigned short* db = dst + ((size_t)b * NN + r * 64) * 64;
  for (int idx = t; idx < 512; idx += 256) {
    int px = idx >> 3, c8 = (idx & 7) * 8;
    *(uint4*)(db + (size_t)px * 64 + c8) = *(const uint4*)&bx[px * LS + c8];
  }
}

// -------- 4. FUSED knorm+gath: normalized dense kc/qc + transposed vt ------
__global__ __launch_bounds__(256) void k_gath(const unsigned short* __restrict__ kxt,
                                              const unsigned short* __restrict__ xt,
                                              const int* __restrict__ qidx, const int* __restrict__ kidx,
                                              const int* __restrict__ nqv, const int* __restrict__ nkv,
                                              const float* __restrict__ gsump,
                                              const float* __restrict__ gsqp,
                                              unsigned short* __restrict__ kc,
                                              unsigned short* __restrict__ vt,
                                              unsigned short* __restrict__ qc) {
  int b = blockIdx.y;
  int j0 = blockIdx.x * 64;
  int nqb = nqv[b], nkb = nkv[b];
  int NKP = (nkb + 63) & ~63, NQP = (nqb + 63) & ~63;
  bool dok = j0 < NKP, doq = j0 < NQP;
  if (!dok && !doq) return;
  __shared__ int li[128];
  __shared__ unsigned short tv[64 * LS];    // V tile for transpose, 9.2 KB
  __shared__ float m2[64], i2[64];
  int t = threadIdx.x;
  if (t < 64) li[t] = (j0 + t < nkb) ? kidx[b * NN + j0 + t] : -1;
  if (t >= 64 && t < 128) li[t] = (j0 + (t - 64) < nqb) ? qidx[b * NN + j0 + (t - 64)] : -1;
  if (t >= 128 && t < 192) {
    int c = t - 128;
    float s = 0.f, s2v = 0.f;
    #pragma unroll 8
    for (int r2 = 0; r2 < 64; ++r2) {
      s   += gsump[((size_t)r2 * BB + b) * 64 + c];
      s2v += gsqp [((size_t)r2 * BB + b) * 64 + c];
    }
    float m = s * (1.f / NN);
    float v = fmaxf(s2v * (1.f / NN) - m * m, 0.f);
    m2[c] = m; i2[c] = rsqrtf(v + 1e-5f);
  }
  __syncthreads();
  const unsigned short* kxb = kxt + (size_t)b * NN * 64;
  const unsigned short* xtb = xt + (size_t)b * NN * 64;
  uint4 z = make_uint4(0u, 0u, 0u, 0u);
  for (int idx = t; idx < 512; idx += 256) {
    int row = idx >> 3, c8 = (idx & 7) * 8;
    size_t dsto = ((size_t)b * NN + j0 + row) * 64 + c8;
    if (dok) {
      int sk = li[row];
      uint4 ko = z;
      if (sk >= 0) {
        uint4 kv = *(const uint4*)(kxb + (size_t)sk * 64 + c8);
        uint4 xv = *(const uint4*)(xtb + (size_t)sk * 64 + c8);
        const unsigned short* ke = (const unsigned short*)&kv;
        const unsigned short* xe = (const unsigned short*)&xv;
        float f[8]; float ss = 0.f;
        #pragma unroll
        for (int j = 0; j < 8; ++j) {
          float v = fmaxf((us2f(ke[j]) - m2[c8 + j]) * i2[c8 + j] + us2f(xe[j]), 0.f);
          f[j] = v; ss += v * v;
        }
        ss += __shfl_xor(ss, 1); ss += __shfl_xor(ss, 2); ss += __shfl_xor(ss, 4);
        float inv = 1.f / (sqrtf(ss) + 1e-8f);
        unsigned short* oe = (unsigned short*)&ko;
        #pragma unroll
        for (int j = 0; j < 8; ++j) oe[j] = f2bu(f[j] * inv);
        *(uint4*)&tv[row * LS + c8] = xv;
      } else {
        float ss = 0.f;
        ss += __shfl_xor(ss, 1); ss += __shfl_xor(ss, 2); ss += __shfl_xor(ss, 4);
        *(uint4*)&tv[row * LS + c8] = z;
      }
      *(uint4*)(kc + dsto) = ko;
    }
    if (doq) {
      int sq = li[64 + row];
      uint4 qo = z;
      if (sq >= 0) {
        uint4 kv = *(const uint4*)(kxb + (size_t)sq * 64 + c8);
        uint4 xv = *(const uint4*)(xtb + (size_t)sq * 64 + c8);
        const unsigned short* ke = (const unsigned short*)&kv;
        const unsigned short* xe = (const unsigned short*)&xv;
        float f[8]; float ss = 0.f;
        #pragma unroll
        for (int j = 0; j < 8; ++j) {
          float v = fmaxf((us2f(ke[j]) - m2[c8 + j]) * i2[c8 + j] + us2f(xe[j]), 0.f);
          f[j] = v; ss += v * v;
        }
        ss += __shfl_xor(ss, 1); ss += __shfl_xor(ss, 2); ss += __shfl_xor(ss, 4);
        float inv = 1.f / (sqrtf(ss) + 1e-8f);
        unsigned short* oe = (unsigned short*)&qo;
        #pragma unroll
        for (int j = 0; j < 8; ++j) oe[j] = f2bu(f[j] * inv);
      } else {
        float ss = 0.f;
        ss += __shfl_xor(ss, 1); ss += __shfl_xor(ss, 2); ss += __shfl_xor(ss, 4);
      }
      *(uint4*)(qc + dsto) = qo;
    }
  }
  __syncthreads();
  if (!dok) return;
  for (int idx = t; idx < 512; idx += 256) {
    int c = idx >> 3, k8 = (idx & 7) * 8;
    unsigned short vals[8];
    #pragma unroll
    for (int j = 0; j < 8; ++j) vals[j] = tv[(k8 + j) * LS + c];
    *(uint4*)(vt + (size_t)b * 262144 + (size_t)c * 4096 + j0 + k8) = *(const uint4*)&vals[0];
  }
}

// -------- 5. attention pass 1: 4 independent waves, zero barriers ----------
__global__ __launch_bounds__(256) void k_att1(const unsigned short* __restrict__ kc,
                                              const unsigned short* __restrict__ vt,
                                              const unsigned short* __restrict__ qc,
                                              const int* __restrict__ nqv, const int* __restrict__ nkv,
                                              unsigned short* __restrict__ afc_part,
                                              float* __restrict__ den_part,
                                              unsigned short* __restrict__ eg) {
  __shared__ unsigned short leb[4][32 * LS];   // per-wave slices, 18.4 KB
  int b = blockIdx.y;
  int nqb = nqv[b], nkb = nkv[b];
  int t = threadIdx.x;
  int wave = t >> 6, lane = t & 63;
  int part = blockIdx.x & (NPARTS - 1);
  int q0 = ((blockIdx.x / NPARTS) * 4 + wave) * 32;   // 32 q rows per wave
  if (q0 >= nqb) return;                          // wave-uniform; no barriers
  int ntiles = (nkb + 63) >> 6;
  int nt_blk = (part < ntiles) ? ((ntiles - part + NPARTS - 1) / NPARTS) : 0;
  int NKP = (nkb + 63) & ~63;                     // E row stride (elements)
  unsigned short* le = leb[wave];
  int l31 = lane & 31, lhi = lane >> 5;
  const unsigned short* kcb = kc + (size_t)b * NN * 64;
  const unsigned short* vtb = vt + (size_t)b * 262144;
  const unsigned short* qcb = qc + (size_t)b * NN * 64;
  unsigned short* egb = eg + (size_t)b * EB_ELEM;
  unsigned short* afcp = afc_part + ((size_t)b * NN) * (NPARTS * 64);
  float* denp = den_part + ((size_t)b * NN) * NDEN;
  short8 aq[4];
  #pragma unroll
  for (int ks = 0; ks < 4; ++ks)
    aq[ks] = *(const short8*)(qcb + (size_t)(q0 + l31) * 64 + ks * 16 + lhi * 8);
  f32x16 pv0, pv1, dsum;
  #pragma unroll
  for (int i = 0; i < 16; ++i) { pv0[i] = 0.f; pv1[i] = 0.f; dsum[i] = 0.f; }
  for (int it = 0; it < nt_blk; ++it) {
    int j0 = (part + it * NPARTS) * 64;
    #pragma unroll
    for (int kh = 0; kh < 2; ++kh) {
      f32x16 s;
      #pragma unroll
      for (int i = 0; i < 16; ++i) s[i] = 0.f;
      const unsigned short* krow = kcb + (size_t)(j0 + kh * 32 + l31) * 64 + lhi * 8;
      #pragma unroll
      for (int ks = 0; ks < 4; ++ks) {
        short8 bk = *(const short8*)(krow + ks * 16);
        s = __builtin_amdgcn_mfma_f32_32x32x16_bf16(aq[ks], bk, s, 0, 0, 0);
      }
      bool kval = (j0 + kh * 32 + l31) < nkb;
      #pragma unroll
      for (int reg = 0; reg < 16; ++reg) {
        float e = kval ? __expf(20.f * s[reg]) : 0.f;
        dsum[reg] += e;
        int row = (reg & 3) + 8 * (reg >> 2) + 4 * lhi;
        le[row * LS + kh * 32 + l31] = f2bu(e);
      }
    }
    #pragma unroll
    for (int ks = 0; ks < 4; ++ks) {
      short8 a = *(const short8*)&le[l31 * LS + ks * 16 + lhi * 8];
      short8 bv0 = *(const short8*)(vtb + (size_t)l31 * 4096 + j0 + ks * 16 + lhi * 8);
      short8 bv1 = *(const short8*)(vtb + (size_t)(32 + l31) * 4096 + j0 + ks * 16 + lhi * 8);
      pv0 = __builtin_amdgcn_mfma_f32_32x32x16_bf16(a, bv0, pv0, 0, 0, 0);
      pv1 = __builtin_amdgcn_mfma_f32_32x32x16_bf16(a, bv1, pv1, 0, 0, 0);
    }
    #pragma unroll
    for (int sub = 0; sub < 4; ++sub) {
      int idx = sub * 64 + lane;
      int q = idx >> 3, cc8 = (idx & 7) * 8;
      if (q0 + q < nqb)
        *(uint4*)(egb + (size_t)(q0 + q) * NKP + j0 + cc8) = *(const uint4*)&le[q * LS + cc8];
    }
  }
  #pragma unroll
  for (int reg = 0; reg < 16; ++reg) {
    float v = dsum[reg];
    v += __shfl_xor(v, 1); v += __shfl_xor(v, 2); v += __shfl_xor(v, 4);
    v += __shfl_xor(v, 8); v += __shfl_xor(v, 16);
    int row = (reg & 3) + 8 * (reg >> 2) + 4 * lhi;
    int qq = q0 + row;
    if (l31 == 0 && qq < nqb) denp[(size_t)qq * NDEN + part] = v;
  }
  #pragma unroll
  for (int reg = 0; reg < 16; ++reg) {
    int row = (reg & 3) + 8 * (reg >> 2) + 4 * lhi;
    int qq = q0 + row;
    if (qq < nqb) {
      unsigned short* ap = afcp + ((size_t)qq * NPARTS + part) * 64;
      ap[l31]      = f2bu(pv0[reg]);
      ap[32 + l31] = f2bu(pv1[reg]);
    }
  }
}

// -------- 6. MERGED post: blocks x<128 = vis column-sum; x>=128 = fusion ---
#define FS 136            // pxa row stride (bf16)
__global__ __launch_bounds__(256) void k_post(const unsigned short* __restrict__ eg,
                                              const float* __restrict__ den_part,
                                              const int* __restrict__ nqv, const int* __restrict__ nkv,
                                              float* __restrict__ visp,
                                              const unsigned short* __restrict__ xt,
                                              const unsigned short* __restrict__ afc_part,
                                              const int* __restrict__ qidx,
                                              const unsigned short* __restrict__ wall,
                                              const float* __restrict__ b2,
                                              float* __restrict__ outp) {
  __shared__ unsigned short pxa[64 * FS];   // 17.4 KB (fusion)
  __shared__ unsigned short f1s[64 * LS];   // 9.2 KB (fusion)
  __shared__ int qpl[64];
  __shared__ float wd[256];                 // 1 KB (vis)
  int b = blockIdx.y;
  int nqb = nqv[b], nkb = nkv[b];
  int t = threadIdx.x;
  if (blockIdx.x < 128) {
    // ---- vis column-sum ----
    int k0 = (blockIdx.x & 15) * 256;
    if (k0 >= nkb) return;
    int NKP = (nkb + 63) & ~63;
    int qpart = blockIdx.x >> 4;
    int qbeg = (qpart * nqb) >> 3;
    int qend = ((qpart + 1) * nqb) >> 3;
    int k = k0 + t;
    const unsigned short* eb = eg + (size_t)b * EB_ELEM;
    float acc = 0.f;
    for (int qc = qbeg; qc < qend; qc += 256) {
      __syncthreads();
      int qq = qc + t;
      float d = 0.f;
      if (qq < qend) {
        const float4* dp = (const float4*)(den_part + ((size_t)b * NN + qq) * NDEN);
        float4 a0 = dp[0], a1 = dp[1], a2 = dp[2], a3 = dp[3];
        d = ((a0.x + a0.y) + (a0.z + a0.w)) + ((a1.x + a1.y) + (a1.z + a1.w))
          + ((a2.x + a2.y) + (a2.z + a2.w)) + ((a3.x + a3.y) + (a3.z + a3.w));
      }
      wd[t] = (d > 0.f) ? 1.f / d : 0.f;
      __syncthreads();
      int lim = min(256, qend - qc);
      if (k < nkb) {
        const unsigned short* ep = eb + (size_t)qc * NKP + k;
        int j = 0;
        for (; j + 8 <= lim; j += 8) {
          #pragma unroll
          for (int u = 0; u < 8; ++u)
            acc += us2f(ep[(size_t)(j + u) * NKP]) * wd[j + u];
        }
        for (; j < lim; ++j)
          acc += us2f(ep[(size_t)j * NKP]) * wd[j];
      }
    }
    if (k < nkb) visp[((size_t)qpart * BB + b) * NN + k] = acc;
    return;
  }
  // ---- fusion epilogue ----
  int q0 = (blockIdx.x - 128) * 64;
  if (q0 >= nqb) return;
  int lane = t & 63;
  int quad = lane >> 4, col = lane & 15;
  int cb = (t >> 6) * 16;                   // wave's co strip
  const int* qix = qidx + b * NN;
  const unsigned short* xtb = xt + (size_t)b * NN * 64;
  const unsigned short* w1b = wall;
  const unsigned short* w2b = wall + 8192;
  const unsigned short* wfb = wall + 12288;
  short8 a1[4], a2[2], af[4];
  #pragma unroll
  for (int kt = 0; kt < 4; ++kt) {
    a1[kt] = *(const short8*)&w1b[(cb + col) * 128 + kt * 32 + quad * 8];
    af[kt] = *(const short8*)&wfb[(cb + col) * 128 + kt * 32 + quad * 8];
  }
  #pragma unroll
  for (int kt = 0; kt < 2; ++kt)
    a2[kt] = *(const short8*)&w2b[(cb + col) * 64 + kt * 32 + quad * 8];
  float b2v[4];
  #pragma unroll
  for (int r = 0; r < 4; ++r) b2v[r] = b2[cb + quad * 4 + r];
  if (t < 64) qpl[t] = (q0 + t < nqb) ? qix[q0 + t] : -1;
  for (int idx = t; idx < 512; idx += 256) {
    int q = idx >> 3, c8 = (idx & 7) * 8;
    int qq = q0 + q;
    uint4 pv = make_uint4(0u, 0u, 0u, 0u);
    unsigned short pa8[8] = {0, 0, 0, 0, 0, 0, 0, 0};
    if (qq < nqb) {
      int qp = qix[qq];
      pv = *(const uint4*)(xtb + (size_t)qp * 64 + c8);
      const float* db = den_part + ((size_t)b * NN + qq) * NDEN;
      float d = 0.f;
      #pragma unroll
      for (int p2 = 0; p2 < NDEN; ++p2) d += db[p2];
      float av[8];
      #pragma unroll
      for (int j = 0; j < 8; ++j) av[j] = 0.f;
      const unsigned short* ab = afc_part + ((size_t)b * NN + qq) * (NPARTS * 64) + c8;
      #pragma unroll
      for (int p2 = 0; p2 < NPARTS; ++p2) {
        const uint4 u = *(const uint4*)(ab + p2 * 64);
        const unsigned short* e8 = (const unsigned short*)&u;
        #pragma unroll
        for (int j = 0; j < 8; ++j) av[j] += us2f(e8[j]);
      }
      float invd = (d > 0.f) ? 1.f / d : 0.f;
      #pragma unroll
      for (int j = 0; j < 8; ++j) pa8[j] = f2bu(av[j] * invd);
    }
    *(uint4*)&pxa[q * FS + c8] = pv;
    *(uint4*)&pxa[q * FS + 64 + c8] = *(const uint4*)&pa8[0];
  }
  __syncthreads();
  #pragma unroll
  for (int qt = 0; qt < 4; ++qt) {
    f32x4 acc = {0.f, 0.f, 0.f, 0.f};
    #pragma unroll
    for (int kt = 0; kt < 4; ++kt) {
      short8 bfrag = *(const short8*)&pxa[(qt * 16 + col) * FS + kt * 32 + quad * 8];
      acc = __builtin_amdgcn_mfma_f32_16x16x32_bf16(a1[kt], bfrag, acc, 0, 0, 0);
    }
    #pragma unroll
    for (int r = 0; r < 4; ++r)
      f1s[(qt * 16 + col) * LS + cb + quad * 4 + r] = f2bu(acc[r]);
  }
  __syncthreads();
  #pragma unroll
  for (int qt = 0; qt < 4; ++qt) {
    f32x4 acc = {0.f, 0.f, 0.f, 0.f};
    #pragma unroll
    for (int kt = 0; kt < 2; ++kt) {
      short8 bfrag = *(const short8*)&f1s[(qt * 16 + col) * LS + kt * 32 + quad * 8];
      acc = __builtin_amdgcn_mfma_f32_16x16x32_bf16(a2[kt], bfrag, acc, 0, 0, 0);
    }
    #pragma unroll
    for (int r = 0; r < 4; ++r) {
      float sg = 1.f / (1.f + __expf(-(acc[r] + b2v[r])));
      int addr = (qt * 16 + col) * FS + 64 + cb + quad * 4 + r;
      pxa[addr] = f2bu(us2f(pxa[addr]) * (1.f - sg));
    }
  }
  __syncthreads();
  #pragma unroll
  for (int qt = 0; qt < 4; ++qt) {
    f32x4 acc = {0.f, 0.f, 0.f, 0.f};
    #pragma unroll
    for (int kt = 0; kt < 4; ++kt) {
      short8 bfrag = *(const short8*)&pxa[(qt * 16 + col) * FS + kt * 32 + quad * 8];
      acc = __builtin_amdgcn_mfma_f32_16x16x32_bf16(af[kt], bfrag, acc, 0, 0, 0);
    }
    int qp = qpl[qt * 16 + col];
    if (qp >= 0) {
      #pragma unroll
      for (int r = 0; r < 4; ++r)
        outp[((size_t)b * CC + cb + quad * 4 + r) * NN + qp] = acc[r];
    }
  }
}

// -------- 7a. sum vis partials, scatter to pixel grid, global max ----------
__global__ __launch_bounds__(256) void k_vmax(const float* __restrict__ visp,
                                              const int* __restrict__ kidx,
                                              const int* __restrict__ nkv,
                                              float* __restrict__ vis,
                                              unsigned int* __restrict__ vmaxb) {
  int i = blockIdx.x * 256 + threadIdx.x;    // < 16384
  int b = i >> 12, k = i & 4095;
  float v = 0.f;
  if (k < nkv[b]) {
    #pragma unroll
    for (int p2 = 0; p2 < 8; ++p2) v += visp[((size_t)p2 * BB + b) * NN + k];
    vis[b * NN + kidx[b * NN + k]] = v;
  }
  #pragma unroll
  for (int off = 32; off > 0; off >>= 1) v = fmaxf(v, __shfl_down(v, off));
  if ((threadIdx.x & 63) == 0) atomicMax(vmaxb, __float_as_uint(v));
}

// -------- 7b. x8 nearest upsample + normalize (float4 stores) --------------
__global__ __launch_bounds__(256) void k_upsample(const float* __restrict__ vis,
                                                  const unsigned int* __restrict__ vmaxb,
                                                  float* __restrict__ out2) {
  int i4 = blockIdx.x * 256 + threadIdx.x;   // < 262144 float4s
  int b = i4 >> 16;
  int rem = i4 & 65535;
  int y = rem >> 7, x4 = (rem & 127) * 4;
  float vm = __uint_as_float(vmaxb[0]);
  if (!(vm > 0.f)) vm = 1.f;
  float v = vis[b * NN + (y >> 3) * 64 + (x4 >> 3)] / vm;
  ((float4*)out2)[i4] = make_float4(v, v, v, v);
}

extern "C" void kernel_launch(void* const* d_in, const int* in_sizes, int n_in,
                              void* d_out, int out_size, void* d_ws, size_t ws_size,
                              hipStream_t stream) {
  const float* x    = (const float*)d_in[0];
  const float* mask = (const float*)d_in[1];
  const float* w1   = (const float*)d_in[2];
  const float* w2c  = (const float*)d_in[3];
  const float* fsw1 = (const float*)d_in[4];
  const float* fsw2 = (const float*)d_in[5];
  const float* fsb2 = (const float*)d_in[6];
  const float* fswf = (const float*)d_in[7];
  float* out = (float*)d_out;
  char* wsb = (char*)d_ws;

  float* vis = (float*)(wsb + WB_VIS);
  int* qidx  = (int*)(wsb + WB_QIX);
  int* kidx  = (int*)(wsb + WB_KIX);
  unsigned char* mfl = (unsigned char*)(wsb + WB_MFL);
  int* nq = (int*)(wsb + WB_CNT);
  int* nk = nq + 4;
  unsigned int* vmaxb = (unsigned int*)(nq + 8);
  unsigned short* wT1 = (unsigned short*)(wsb + WB_WT1);
  unsigned short* wT2 = (unsigned short*)(wsb + WB_WT2);
  unsigned short* wall = (unsigned short*)(wsb + WB_WFB);
  unsigned short* y1t = (unsigned short*)(wsb + WB_Y1T);   // conv scratch
  unsigned short* xt  = (unsigned short*)(wsb + WB_XT);
  unsigned short* kxt = (unsigned short*)(wsb + WB_KXT);
  unsigned short* kc  = (unsigned short*)(wsb + WB_KC);
  unsigned short* vt  = (unsigned short*)(wsb + WB_VT);
  unsigned short* qc  = (unsigned short*)(wsb + WB_QC);
  unsigned short* eg  = (unsigned short*)(wsb + WB_E);
  unsigned short* afc_part = (unsigned short*)(wsb + WB_AFCP);
  float* den_part = (float*)(wsb + WB_DENP);
  float* visp     = (float*)(wsb + WB_VISP);
  float* gsum1p = (float*)(wsb + WB_GST);
  float* gsq1p  = (float*)(wsb + WB_GST + 65536);
  float* gsum2p = (float*)(wsb + WB_GST + 131072);
  float* gsq2p  = (float*)(wsb + WB_GST + 196608);

  k_pre<<<512, 256, 0, stream>>>(x, mask, w1, w2c, fsw1, fsw2, fswf,
                                 out, xt, mfl, vis, vmaxb, wT1, wT2, wall);
  k_conv1c<<<dim3(65, BB), 256, 0, stream>>>(xt, wT1, y1t, gsum1p, gsq1p,
                                             mfl, qidx, kidx, nq, nk);
  k_convm2<<<dim3(64, BB), 256, 0, stream>>>(y1t, wT2, gsum1p, gsq1p, kxt, gsum2p, gsq2p);
  k_gath<<<dim3(64, BB), 256, 0, stream>>>(kxt, xt, qidx, kidx, nq, nk, gsum2p, gsq2p, kc, vt, qc);
  k_att1<<<dim3(32 * NPARTS, BB), 256, 0, stream>>>(kc, vt, qc, nq, nk, afc_part, den_part, eg);
  k_post<<<dim3(192, BB), 256, 0, stream>>>(eg, den_part, nq, nk, visp,
                                            xt, afc_part, qidx, wall, fsb2, out);
  k_vmax<<<64, 256, 0, stream>>>(visp, kidx, nk, vis, vmaxb);
  k_upsample<<<1024, 256, 0, stream>>>(vis, vmaxb, out + 1048576);
}